// Round 6
// baseline (73.499 us; speedup 1.0000x reference)
//
#include <hip/hip_runtime.h>
#include <hip/hip_bf16.h>
#include <math.h>

#define NB 4096
#define NV 778
#define NJ 16
#define NC 30
#define NS 10
#define NF 1538
#define VC3 (NV*3)          // 2334
#define JVROW (799*3)       // 2397 floats per batch in jv
#define KPAD 160            // padded K (135 pose + 10 shape + 1 template)
#define NPAD 2496           // padded vc (13 * 192)
#define FROW (NF*3)         // 4614
#define BT 16               // batch tile for gemm kernel

// output float offsets
#define OUT_JV    0
#define OUT_FACES (NB*799*3)                 // 9,818,112
#define OUT_POSES (OUT_FACES + NB*NF*3)      // 28,717,056

// ws layout
#define WS_JT   0                            // 48 f32
#define WS_JS   48                           // 480 f32
#define WS_AR   528                          // NB*192 f32 = 786432
#define WA_BYTES 3147840                     // NB*160 bf16 = 1,310,720 B
#define WB_BYTES 4458560                     // NPAD*160 bf16 = 798,720 B
// end 5,257,280 B

typedef __attribute__((ext_vector_type(8))) short bf16x8;
typedef __attribute__((ext_vector_type(4))) float f32x4;

__device__ const int d_pos16[16] = {0,1,2,3,5,6,7,9,10,11,13,14,15,17,18,19};

// ---------------- kernel 1: consts (blocks 0..131) + buildB (blocks 132..1691) ----------------
__global__ __launch_bounds__(256) void k_prep(const float* __restrict__ jr,
                                              const float* __restrict__ vt,
                                              const float* __restrict__ sd,
                                              const float* __restrict__ pdin,
                                              float* __restrict__ ws,
                                              __hip_bfloat16* __restrict__ WB)
{
    int blk = blockIdx.x;
    if (blk < 132) {
        int w = (blk * 256 + threadIdx.x) >> 6;
        int lane = threadIdx.x & 63;
        if (w >= 528) return;
        float acc = 0.f;
        if (w < 48) {
            int j = w / 3, c = w % 3;
            for (int v = lane; v < NV; v += 64) acc += jr[j*NV + v] * vt[v*3 + c];
        } else {
            int q = w - 48;
            int j = q / 30, rem = q % 30, c = rem / 10, s = rem % 10;
            for (int v = lane; v < NV; v += 64) acc += jr[j*NV + v] * sd[v*30 + c*10 + s];
        }
        for (int off = 32; off; off >>= 1) acc += __shfl_down(acc, off);
        if (lane == 0) ws[w] = acc;
    } else {
        int idx = (blk - 132) * 256 + threadIdx.x;
        if (idx >= NPAD * KPAD) return;
        int row = idx / KPAD, k = idx % KPAD;
        float val = 0.f;
        if (row < VC3) {
            if (k < 135) val = pdin[(size_t)row*135 + k];
            else if (k < 145) { int v = row/3, c = row%3; val = sd[v*30 + c*10 + (k-135)]; }
            else if (k == 145) val = vt[row];
        }
        WB[idx] = __float2bfloat16(val);
    }
}

// ---------------- kernel 2: per-batch pose/FK + A-row (bf16) + faces row ----------------
__global__ __launch_bounds__(64) void k_batch(const float* __restrict__ rot,
                                              const float* __restrict__ pp,
                                              const float* __restrict__ sp,
                                              const float* __restrict__ hc,
                                              const float* __restrict__ hm,
                                              const int* __restrict__ faces,
                                              float* __restrict__ ws,
                                              float* __restrict__ out)
{
    __shared__ float poses_s[48];
    __shared__ float R_s[16][9];
    __shared__ float Jp_s[48];
    __shared__ float A_s[16][12];
    float* ar_ws = ws + WS_AR;
    __hip_bfloat16* WA = (__hip_bfloat16*)((char*)ws + WA_BYTES);

    int b = blockIdx.x, t = threadIdx.x;

    if (t < 3) poses_s[t] = rot[b*3 + t];
    if (t < 45) {
        float a = hm[t];
        for (int s = 0; s < NC; s++) a += pp[b*NC + s] * hc[s*45 + t];
        poses_s[3 + t] = a;
    }
    __syncthreads();
    if (t < 48) out[OUT_POSES + (size_t)b*48 + t] = poses_s[t];

    // faces broadcast row for this batch (nontemporal: pure streaming writes)
    {
        float* fo = out + OUT_FACES + (size_t)b * FROW;
        for (int i = t; i < FROW/2; i += 64) {
            __builtin_nontemporal_store((float)faces[2*i],     fo + 2*i);
            __builtin_nontemporal_store((float)faces[2*i + 1], fo + 2*i + 1);
        }
    }

    if (t < 48) {
        float a = ws[WS_JT + t];
        const float* js = ws + WS_JS + t*10;
        float acc = a;
        for (int s = 0; s < NS; s++) acc += js[s] * sp[b*NS + s];
        Jp_s[t] = acc;
    }
    if (t < 16) {
        float x = poses_s[t*3], y = poses_s[t*3+1], z = poses_s[t*3+2];
        float th = sqrtf(x*x + y*y + z*z + 1e-8f);
        float kx = x/th, ky = y/th, kz = z/th;
        float s = sinf(th), c = cosf(th), oc = 1.f - c;
        float* R = R_s[t];
        R[0] = 1.f + oc*(-(ky*ky + kz*kz));
        R[1] = -s*kz + oc*(kx*ky);
        R[2] =  s*ky + oc*(kx*kz);
        R[3] =  s*kz + oc*(kx*ky);
        R[4] = 1.f + oc*(-(kx*kx + kz*kz));
        R[5] = -s*kx + oc*(ky*kz);
        R[6] = -s*ky + oc*(kx*kz);
        R[7] =  s*kx + oc*(ky*kz);
        R[8] = 1.f + oc*(-(kx*kx + ky*ky));
    }
    __syncthreads();

    // A-matrix row for GEMM: [pw(135) | sp(10) | 1 | zeros]
    for (int i = t; i < KPAD; i += 64) {
        float val;
        if (i < 135) {
            int j = 1 + i/9, e = i % 9;
            val = R_s[j][e] - ((e == 0 || e == 4 || e == 8) ? 1.f : 0.f);
        } else if (i < 145) val = sp[b*NS + (i - 135)];
        else if (i == 145) val = 1.0f;
        else val = 0.f;
        WA[(size_t)b*KPAD + i] = __float2bfloat16(val);
    }

    if (t < 12) {
        int r = t >> 2, c = t & 3;
        A_s[0][t] = (c < 3) ? R_s[0][r*3 + c] : Jp_s[r];
    }
    __syncthreads();
    const int par[16] = {0,0,1,2,0,4,5,0,7,8,0,10,11,0,13,14};
    #pragma unroll
    for (int i = 1; i < 16; i++) {
        int p = par[i];
        if (t < 12) {
            int r = t >> 2, c = t & 3;
            float val;
            if (c < 3) {
                val = A_s[p][r*4+0]*R_s[i][0*3+c]
                    + A_s[p][r*4+1]*R_s[i][1*3+c]
                    + A_s[p][r*4+2]*R_s[i][2*3+c];
            } else {
                float t0 = Jp_s[i*3+0] - Jp_s[p*3+0];
                float t1 = Jp_s[i*3+1] - Jp_s[p*3+1];
                float t2 = Jp_s[i*3+2] - Jp_s[p*3+2];
                val = A_s[p][r*4+0]*t0 + A_s[p][r*4+1]*t1
                    + A_s[p][r*4+2]*t2 + A_s[p][r*4+3];
            }
            A_s[i][t] = val;
        }
        __syncthreads();
    }

    if (t < 48) {
        int j = t / 3, r = t % 3;
        out[OUT_JV + (size_t)b*JVROW + d_pos16[j]*3 + r] = A_s[j][r*4 + 3];
    }
    for (int i = t; i < 192; i += 64) {
        int j = i / 12, rc = i % 12, r = rc >> 2, c = rc & 3;
        float val = A_s[j][r*4 + c];
        if (c == 3) {
            val -= A_s[j][r*4+0]*Jp_s[j*3+0]
                 + A_s[j][r*4+1]*Jp_s[j*3+1]
                 + A_s[j][r*4+2]*Jp_s[j*3+2];
        }
        ar_ws[(size_t)b*192 + i] = val;
    }
}

// ---------------- kernel 3: fused GEMM (v_posed) + LBS epilogue ----------------
// Tile: 16 batches x 192 cols, 256 thr = 4 waves (one 48-col quarter each).
// Fragments direct from global (L2-hot). LDS only C redistribution: 16x197 f32 = 12.6 KB.
__global__ __launch_bounds__(256, 6) void k_gemm_lbs(const ushort* __restrict__ WA,
                                                     const ushort* __restrict__ WB,
                                                     const float* __restrict__ ar,
                                                     const float* __restrict__ wts,
                                                     float* __restrict__ out)
{
    __shared__ __align__(16) float Cs[BT][197];

    // XCD-bijective swizzle: 3328 blocks = 8 XCDs x 416
    int bid = blockIdx.x;
    int swz = (bid & 7) * 416 + (bid >> 3);
    int bx = swz % 13, by = swz / 13;
    int n0 = bx * 192, b0 = by * BT;

    int tid = threadIdx.x;
    int wv = __builtin_amdgcn_readfirstlane(tid >> 6);   // wave id 0..3
    int lane = tid & 63;
    int wn = wv;               // 48-col quarter
    int l15 = lane & 15, lk = (lane >> 4) * 8;

    const ushort* Abase = WA + (size_t)(b0 + l15)*KPAD + lk;
    const ushort* Bbase = WB + (size_t)(n0 + wn*48 + l15)*KPAD + lk;

    f32x4 acc[3] = {};
    #pragma unroll
    for (int ks = 0; ks < 5; ks++) {
        bf16x8 a, bf[3];
        a = *(const bf16x8*)(Abase + ks*32);
        #pragma unroll
        for (int ni = 0; ni < 3; ni++)
            bf[ni] = *(const bf16x8*)(Bbase + (size_t)ni*16*KPAD + ks*32);
        #pragma unroll
        for (int ni = 0; ni < 3; ni++)
            acc[ni] = __builtin_amdgcn_mfma_f32_16x16x32_bf16(a, bf[ni], acc[ni], 0, 0, 0);
    }

    // scatter C tile to LDS (row = batch-local, col = n-local; stride 197)
    #pragma unroll
    for (int ni = 0; ni < 3; ni++)
        #pragma unroll
        for (int r = 0; r < 4; r++)
            Cs[4*(lane>>4) + r][wn*48 + ni*16 + l15] = acc[ni][r];
    __syncthreads();

    // LBS epilogue: lane = local vertex, each wave does 4 batches
    int vloc = lane;
    int v = bx*64 + vloc;
    bool vok = (v < NV);
    float w16[16];
    if (vok) {
        #pragma unroll
        for (int j = 0; j < 16; j++) w16[j] = wts[(size_t)v*16 + j];
    } else {
        #pragma unroll
        for (int j = 0; j < 16; j++) w16[j] = 0.f;
    }

    int fp = (v == 320) ? 4 : (v == 443) ? 8 : (v == 672) ? 12
           : (v == 555) ? 16 : (v == 744) ? 20 : -1;

    #pragma unroll 2
    for (int bi = 0; bi < 4; bi++) {
        int bloc = wv*4 + bi;
        int b = b0 + bloc;
        const float* arb = ar + (size_t)b * 192;   // wave-uniform -> s_load
        float x = Cs[bloc][3*vloc + 0];
        float y = Cs[bloc][3*vloc + 1];
        float z = Cs[bloc][3*vloc + 2];
        float m[12];
        #pragma unroll
        for (int k = 0; k < 12; k++) m[k] = 0.f;
        #pragma unroll
        for (int j = 0; j < 16; j++) {
            float wj = w16[j];
            #pragma unroll
            for (int k = 0; k < 12; k++) m[k] += wj * arb[j*12 + k];
        }
        if (vok) {
            float o0 = m[0]*x + m[1]*y + m[2]*z  + m[3];
            float o1 = m[4]*x + m[5]*y + m[6]*z  + m[7];
            float o2 = m[8]*x + m[9]*y + m[10]*z + m[11];
            size_t base = OUT_JV + (size_t)b*JVROW + (size_t)(21 + v)*3;
            out[base + 0] = o0; out[base + 1] = o1; out[base + 2] = o2;
            if (fp >= 0) {
                size_t jb = OUT_JV + (size_t)b*JVROW + (size_t)fp*3;
                out[jb + 0] = o0; out[jb + 1] = o1; out[jb + 2] = o2;
            }
        }
    }
}

extern "C" void kernel_launch(void* const* d_in, const int* in_sizes, int n_in,
                              void* d_out, int out_size, void* d_ws, size_t ws_size,
                              hipStream_t stream)
{
    const float* rot  = (const float*)d_in[0];
    const float* pp   = (const float*)d_in[1];
    const float* sp   = (const float*)d_in[2];
    const float* vt   = (const float*)d_in[3];
    const float* sd   = (const float*)d_in[4];
    const float* pdir = (const float*)d_in[5];
    const float* jr   = (const float*)d_in[6];
    const float* wts  = (const float*)d_in[7];
    const float* hc   = (const float*)d_in[8];
    const float* hm   = (const float*)d_in[9];
    const int*   faces= (const int*)d_in[10];
    float* out = (float*)d_out;
    float* ws  = (float*)d_ws;

    const ushort* WA = (const ushort*)((char*)d_ws + WA_BYTES);
    const ushort* WB = (const ushort*)((char*)d_ws + WB_BYTES);

    k_prep<<<132 + (NPAD*KPAD + 255)/256, 256, 0, stream>>>(jr, vt, sd, pdir, ws,
                (__hip_bfloat16*)((char*)d_ws + WB_BYTES));
    k_batch<<<NB, 64, 0, stream>>>(rot, pp, sp, hc, hm, faces, ws, out);
    k_gemm_lbs<<<13 * (NB/BT), 256, 0, stream>>>(WA, WB, ws + WS_AR, wts, out);
}